// Round 2
// 29074.768 us; speedup vs baseline: 1.0256x; 1.0256x over previous
//
#include <hip/hip_runtime.h>

// PRPN forward, MI355X. fp32 in/out, fp32 state, f16 MFMA GEMMs.
// T=256, B=64, H=1024, NSLOTS=15, NLAYERS=2.
//
// Persistent-scan version: ONE plain-launched kernel (grid=256 blocks, 256
// threads; 14KB LDS + 4 waves/block => all blocks provably co-resident on the
// 256-CU MI355X, so a hand-rolled grid barrier is safe WITHOUT the cooperative
// API, which silently failed under graph capture last round).
// Rings are 16 slots (write slot (t+15)&15 disjoint from the 15 read slots):
//   prologue: cell0(0)
//   per t:  P2 [bundleA(t) blocks 0..159 || pred(t-1) blocks 160..223]
//           P3 [cell1(t) all 256 blocks]
//           P4 [bundleB(t) blocks 0..111 || cell0(t+1) blocks 112..239]
//   tail:   pred(255)
// => 3 grid barriers per step instead of 5 kernel launches.

typedef _Float16 half8 __attribute__((ext_vector_type(8)));
typedef float f32x4 __attribute__((ext_vector_type(4)));

#define LSTR 56  // LDS row stride (f16): 112B rows -> 16B aligned, 2-way (free) banks

__device__ __forceinline__ float sigm(float x) { return 1.0f / (1.0f + expf(-x)); }

__device__ __forceinline__ void store_ct(float* p, float v)    { *p = v; }
__device__ __forceinline__ void store_ct(_Float16* p, float v) { *p = (_Float16)v; }

// ---------- shared 64x64 f16 MFMA mainloop: C_tile = A_tile @ B_tile^T ----------
// A: M x K row-major (lda), B: N x K row-major (ldb). Single LDS buffer,
// 1-deep register prefetch: k+1's global loads issued before k's MFMAs so the
// L2 latency hides under compute + the next barrier.
__device__ __forceinline__ void mfma_loop(const _Float16* __restrict__ Ag, int lda,
                                          const _Float16* __restrict__ Bg, int ldb,
                                          int K, _Float16* As, _Float16* Bs, f32x4* acc)
{
  const int tid = threadIdx.x;
  const int lr  = tid >> 2;          // 0..63 : row loaded by this thread
  const int lc  = (tid & 3) << 3;    // 0,8,16,24 : k-chunk
  const int ln  = tid & 63;
  const int wv  = tid >> 6;          // wave 0..3 -> M rows [16w,16w+16)
  const int m15 = ln & 15;
  const int q   = ln >> 4;
  const _Float16* ap = Ag + (size_t)lr * lda + lc;
  const _Float16* bp = Bg + (size_t)lr * ldb + lc;
  _Float16* asw = As + lr * LSTR + lc;
  _Float16* bsw = Bs + lr * LSTR + lc;
  const _Float16* asr = As + (wv * 16 + m15) * LSTR + q * 8;
  const _Float16* bsr = Bs + m15 * LSTR + q * 8;
  half8 av = *(const half8*)ap;
  half8 bv = *(const half8*)bp;
  for (int k0 = 0; k0 < K; k0 += 32) {
    __syncthreads();
    *(half8*)asw = av;
    *(half8*)bsw = bv;
    __syncthreads();
    if (k0 + 32 < K) {               // prefetch next k-chunk (in flight during MFMAs)
      ap += 32; bp += 32;
      av = *(const half8*)ap;
      bv = *(const half8*)bp;
    }
    half8 a = *(const half8*)asr;
#pragma unroll
    for (int j = 0; j < 4; j++) {
      half8 b = *(const half8*)(bsr + j * 16 * LSTR);
      acc[j] = __builtin_amdgcn_mfma_f32_16x16x32_f16(a, b, acc[j], 0, 0, 0);
    }
  }
}

// ---------- generic GEMM: C[M,N] = A @ B^T (+ epilogue) ---------- (setup/epilogue only)
// ACT 0: acc + p0?[n] + p1?[n]
// ACT 1: relu(p0[n]*(acc+p1[n])+p2[n])
// ACT 2: tanh(p0[n]*(acc+p1[n])+p2[n])
template <int ACT, typename CT>
__global__ __launch_bounds__(256) void gemm_bt(const _Float16* __restrict__ A, int lda,
                                               const _Float16* __restrict__ B, int ldb,
                                               CT* __restrict__ C, int ldc, int K,
                                               const float* __restrict__ p0,
                                               const float* __restrict__ p1,
                                               const float* __restrict__ p2)
{
  __shared__ __align__(16) _Float16 As[64 * LSTR];
  __shared__ __align__(16) _Float16 Bs[64 * LSTR];
  f32x4 acc[4] = {};
  const int ntile = blockIdx.x, mtile = blockIdx.y;
  mfma_loop(A + (size_t)mtile * 64 * lda, lda, B + (size_t)ntile * 64 * ldb, ldb, K, As, Bs, acc);
  const int ln = threadIdx.x & 63, wv = threadIdx.x >> 6;
  const int m15 = ln & 15, q = ln >> 4;
#pragma unroll
  for (int j = 0; j < 4; j++) {
    const int col = ntile * 64 + j * 16 + m15;
    float b0 = 0.f, b1 = 0.f, b2 = 0.f;
    if (ACT == 0) {
      if (p0) b0 = p0[col];
      if (p1) b0 += p1[col];
    } else {
      b0 = p0[col]; b1 = p1[col]; b2 = p2[col];
    }
#pragma unroll
    for (int r = 0; r < 4; r++) {
      const int row = mtile * 64 + wv * 16 + q * 4 + r;
      float v = acc[j][r];
      if (ACT == 0) v += b0;
      else {
        v = b0 * (v + b1) + b2;
        v = (ACT == 1) ? fmaxf(v, 0.f) : tanhf(v);
      }
      store_ct(&C[(size_t)row * ldc + col], v);
    }
  }
}

// ---------- persistent-scan building blocks ----------
struct SegP { const _Float16* B; float* C; const float* b1; const float* b2; int ldb; int ldc; };

__device__ void bundle_tile(const _Float16* __restrict__ A, const SegP sg, int ntile,
                            _Float16* As, _Float16* Bs)
{
  f32x4 acc[4] = {};
  mfma_loop(A, 1024, sg.B + (size_t)ntile * 64 * sg.ldb, sg.ldb, 1024, As, Bs, acc);
  const int ln = threadIdx.x & 63, wv = threadIdx.x >> 6;
  const int m15 = ln & 15, q = ln >> 4;
#pragma unroll
  for (int j = 0; j < 4; j++) {
    const int col = ntile * 64 + j * 16 + m15;
    float bb = 0.f;
    if (sg.b1) bb += sg.b1[col];
    if (sg.b2) bb += sg.b2[col];
#pragma unroll
    for (int r = 0; r < 4; r++) {
      const int row = wv * 16 + q * 4 + r;
      sg.C[(size_t)row * sg.ldc + col] = acc[j][r] + bb;
    }
  }
}

// attention + LSTM cell for channel chunk [c0,c0+nch) of batch b.
// Rings have 16 slots; reads use slots (t+s)&15 (s<15), write slot (t+15)&15.
template <typename KT, typename GT>
__device__ void cell_body(int b, int c0, int nch, int t,
    const KT* __restrict__ keyA, const float* __restrict__ keyB,
    const GT* __restrict__ gatesIn,
    const float* __restrict__ ringH, const float* __restrict__ ringC,
    const float* __restrict__ proj, const float* __restrict__ mask,
    float* __restrict__ hRingOut, float* __restrict__ cRingOut,
    _Float16* __restrict__ hHalf, float* s_key, float* s_att)
{
  const int tid = threadIdx.x;
  for (int i = tid; i < 1024; i += 256)
    s_key[i] = (float)keyA[b * 1024 + i] + keyB[b * 1024 + i];
  __syncthreads();
  const int wv = tid >> 6, ln = tid & 63;
  for (int s = wv; s < 15; s += 4) {
    const float* hr = ringH + ((size_t)((t + s) & 15) * 64 + b) * 1024;
    float p = 0.f;
    for (int i = ln; i < 1024; i += 64) p = fmaf(hr[i], s_key[i], p);
    for (int off = 32; off > 0; off >>= 1) p += __shfl_down(p, off, 64);
    if (ln == 0) s_att[s] = p * 0.03125f;  // 1/sqrt(1024)
  }
  __syncthreads();
  if (tid == 0) {
    float mx = -1e30f;
    for (int s = 0; s < 15; s++) mx = fmaxf(mx, s_att[s]);
    float den = 1e-8f, e[15];
    for (int s = 0; s < 15; s++) { e[s] = expf(s_att[s] - mx) * mask[b * 15 + s]; den += e[s]; }
    float inv = 1.f / den;
    for (int s = 0; s < 15; s++) s_att[s] = e[s] * inv;
  }
  __syncthreads();
  float att[15];
  int poff[15], coff[15];
#pragma unroll
  for (int s = 0; s < 15; s++) {
    att[s] = s_att[s];
    const int phs = (t + s) & 15;
    poff[s] = phs * 262144 + b * 4096;  // proj ring [16][64][4096]
    coff[s] = phs * 65536 + b * 1024;   // c ring    [16][64][1024]
  }
  for (int c = c0 + tid; c < c0 + nch; c += 256) {
    float g[4];
#pragma unroll
    for (int gi = 0; gi < 4; gi++) {
      const int gidx = gi * 1024 + c;
      float a = (float)gatesIn[(size_t)b * 4096 + gidx];
      for (int s = 0; s < 15; s++) a = fmaf(att[s], proj[(size_t)poff[s] + gidx], a);
      g[gi] = a;
    }
    float selc = 0.f;
    for (int s = 0; s < 15; s++) selc = fmaf(att[s], ringC[(size_t)coff[s] + c], selc);
    const float ig = sigm(g[0]), fg = sigm(g[1]), gg = tanhf(g[2]), og = sigm(g[3]);
    const float cn = fg * selc + ig * gg;
    const float h  = og * tanhf(cn);
    cRingOut[b * 1024 + c] = cn;
    hRingOut[b * 1024 + c] = h;
    hHalf[b * 1024 + c]    = (_Float16)h;
  }
}

// prediction attention for chunk [c0,c0+nch) of batch b at time t.
// Reads pm = ringH1 slots (t+s)&15 (pre-append view); h1_t is at slot (t+15)&15.
__device__ void pred_body(int b, int c0, int nch, int t,
    const float* __restrict__ keyA, const float* __restrict__ keyB,
    const float* __restrict__ ringH, const float* __restrict__ mask,
    _Float16* __restrict__ xrow, float* s_key, float* s_att)
{
  const int tid = threadIdx.x;
  for (int i = tid; i < 1024; i += 256)
    s_key[i] = keyA[b * 1024 + i] + keyB[b * 1024 + i];
  __syncthreads();
  const int wv = tid >> 6, ln = tid & 63;
  for (int s = wv; s < 15; s += 4) {
    const float* hr = ringH + ((size_t)((t + s) & 15) * 64 + b) * 1024;
    float p = 0.f;
    for (int i = ln; i < 1024; i += 64) p = fmaf(hr[i], s_key[i], p);
    for (int off = 32; off > 0; off >>= 1) p += __shfl_down(p, off, 64);
    if (ln == 0) s_att[s] = p * 0.03125f;
  }
  __syncthreads();
  if (tid == 0) {
    float mx = -1e30f;
    for (int s = 0; s < 15; s++) mx = fmaxf(mx, s_att[s]);
    float den = 1e-8f, e[15];
    for (int s = 0; s < 15; s++) { e[s] = expf(s_att[s] - mx) * mask[b * 15 + s]; den += e[s]; }
    float inv = 1.f / den;
    for (int s = 0; s < 15; s++) s_att[s] = e[s] * inv;
  }
  __syncthreads();
  float att[15];
  int hoff[15];
#pragma unroll
  for (int s = 0; s < 15; s++) { att[s] = s_att[s]; hoff[s] = ((t + s) & 15) * 65536 + b * 1024; }
  const float* hNew = ringH + (size_t)((t + 15) & 15) * 65536 + b * 1024;
  for (int c = c0 + tid; c < c0 + nch; c += 256) {
    float sel = 0.f;
    for (int s = 0; s < 15; s++) sel = fmaf(att[s], ringH[(size_t)hoff[s] + c], sel);
    const float h = hNew[c];
    xrow[(size_t)b * 2048 + c]        = (_Float16)h;
    xrow[(size_t)b * 2048 + 1024 + c] = (_Float16)sel;
  }
}

// ---------- grid barrier: distributed arrive flags + master-gathered release ----------
// arrive[bid*32] (128B-strided, no contention), release at arrive+8192.
// Relaxed agent-scope atomic spins (performed at coherent LLC); one
// __threadfence() per block per barrier on each side gives release/acquire
// (L2 writeback before publish, L1/L2 invalidate after observe).
__device__ __forceinline__ void gsync(unsigned* arrive, unsigned* release, unsigned ph, int bid)
{
  __syncthreads();
  const int tid = threadIdx.x;
  if (bid == 0) {
    if (tid >= 1) {  // thread i waits for block i
      while (__hip_atomic_load(&arrive[tid << 5], __ATOMIC_RELAXED, __HIP_MEMORY_SCOPE_AGENT) < ph)
        __builtin_amdgcn_s_sleep(1);
    }
    __syncthreads();
    if (tid == 0) {
      __threadfence();   // writeback block0's data + invalidate stale caches
      __hip_atomic_store(release, ph, __ATOMIC_RELAXED, __HIP_MEMORY_SCOPE_AGENT);
    }
    __syncthreads();
  } else {
    if (tid == 0) {
      __threadfence();   // publish this block's phase writes
      __hip_atomic_store(&arrive[bid << 5], ph, __ATOMIC_RELAXED, __HIP_MEMORY_SCOPE_AGENT);
      while (__hip_atomic_load(release, __ATOMIC_RELAXED, __HIP_MEMORY_SCOPE_AGENT) < ph)
        __builtin_amdgcn_s_sleep(1);
      __threadfence();   // invalidate: see other blocks' data
    }
    __syncthreads();
  }
}

struct ScanArgs {
  const _Float16 *embkey, *embgates, *wihF, *whhF, *wsmF, *wpdF;
  const float *mg, *mgn, *bih, *bhh, *bsm, *bpd;
  float *ringH0, *ringC0, *ringH1, *ringC1, *P0, *P1;
  float *kc0, *kc1, *kcp0, *kcp1, *key1s, *gates1i, *keypred;
  _Float16 *h0h, *h1h, *xbuf;
  unsigned *bar;
};

__global__ __launch_bounds__(256, 1) void k_scan(ScanArgs A)
{
  __shared__ __align__(16) _Float16 As[64 * LSTR];
  __shared__ __align__(16) _Float16 Bs[64 * LSTR];
  float* s_key = (float*)As;   // 4KB of the 7KB As
  float* s_att = (float*)Bs;
  const int bid = blockIdx.x;
  unsigned* arrive  = A.bar;
  unsigned* release = A.bar + 8192;
  unsigned ph = 0;

  // prologue: cell0(0), all 256 blocks, 4 per batch
  cell_body<_Float16, _Float16>(bid >> 2, (bid & 3) << 8, 256, 0,
      A.embkey, A.kc0, A.embgates, A.ringH0, A.ringC0, A.P0, A.mg,
      A.ringH0 + (size_t)15 * 65536, A.ringC0 + (size_t)15 * 65536, A.h0h, s_key, s_att);
  gsync(arrive, release, ++ph, bid);

  for (int t = 0; t < 256; ++t) {
    const int w15 = (t + 15) & 15;
    // ---- P2: bundleA(t) [0..159] || pred(t-1) [160..223] ----
    if (bid < 160) {
      SegP sg; int nt;
      if (bid < 64)       { sg = SegP{A.whhF,                 A.P0 + (size_t)w15 * 262144, nullptr,      nullptr,      1024, 4096}; nt = bid; }
      else if (bid < 80)  { sg = SegP{A.wsmF + 1024,          A.kc0,                       nullptr,      nullptr,      2048, 1024}; nt = bid - 64; }
      else if (bid < 144) { sg = SegP{A.wihF + 4194304,       A.gates1i,                   A.bih + 4096, A.bhh + 4096, 1024, 4096}; nt = bid - 80; }
      else                { sg = SegP{A.wsmF + 2097152,       A.key1s,                     A.bsm + 1024, nullptr,      2048, 1024}; nt = bid - 144; }
      bundle_tile(A.h0h, sg, nt, As, Bs);
    } else if (bid < 224 && t > 0) {
      pred_body(bid - 160, 0, 1024, t - 1, A.keypred, ((t - 1) & 1) ? A.kcp0 : A.kcp1,
                A.ringH1, A.mgn + (size_t)(t - 1) * 960, A.xbuf + (size_t)(t - 1) * 131072, s_key, s_att);
    }
    gsync(arrive, release, ++ph, bid);
    // ---- P3: cell1(t), all 256 blocks ----
    cell_body<float, float>(bid >> 2, (bid & 3) << 8, 256, t,
        A.key1s, A.kc1, A.gates1i, A.ringH1, A.ringC1, A.P1, A.mg + (size_t)t * 960,
        A.ringH1 + (size_t)w15 * 65536, A.ringC1 + (size_t)w15 * 65536, A.h1h, s_key, s_att);
    gsync(arrive, release, ++ph, bid);
    // ---- P4: bundleB(t) [0..111] || cell0(t+1) [112..239] ----
    if (bid < 112) {
      SegP sg; int nt;
      float* kcpW = (t & 1) ? A.kcp1 : A.kcp0;
      if (bid < 64)       { sg = SegP{A.whhF + 4194304,        A.P1 + (size_t)w15 * 262144, nullptr, nullptr, 1024, 4096}; nt = bid; }
      else if (bid < 80)  { sg = SegP{A.wsmF + 2097152 + 1024, A.kc1,                       nullptr, nullptr, 2048, 1024}; nt = bid - 64; }
      else if (bid < 96)  { sg = SegP{A.wpdF,                  A.keypred,                   A.bpd,   nullptr, 2048, 1024}; nt = bid - 80; }
      else                { sg = SegP{A.wpdF + 1024,           kcpW,                        nullptr, nullptr, 2048, 1024}; nt = bid - 96; }
      bundle_tile(A.h1h, sg, nt, As, Bs);
    } else if (bid < 240 && t < 255) {
      const int bb = (bid - 112) >> 1, c0 = ((bid - 112) & 1) << 9;
      cell_body<_Float16, _Float16>(bb, c0, 512, t + 1,
          A.embkey + (size_t)(t + 1) * 65536, A.kc0, A.embgates + (size_t)(t + 1) * 262144,
          A.ringH0, A.ringC0, A.P0, A.mg + (size_t)(t + 1) * 960,
          A.ringH0 + (size_t)(t & 15) * 65536, A.ringC0 + (size_t)(t & 15) * 65536, A.h0h, s_key, s_att);
    }
    gsync(arrive, release, ++ph, bid);
  }
  // tail: pred(255), all 256 blocks ((255&1)?kcp0:kcp1 -> kcp0)
  pred_body(bid >> 2, (bid & 3) << 8, 256, 255, A.keypred, A.kcp0,
            A.ringH1, A.mgn + (size_t)255 * 960, A.xbuf + (size_t)255 * 131072, s_key, s_att);
}

// ---------- small setup kernels ----------
__global__ void k_zero(float* __restrict__ p, int n) {
  int i = blockIdx.x * 256 + threadIdx.x;
  const int st = gridDim.x * 256;
  for (; i < n; i += st) p[i] = 0.f;
}

__global__ void k_cvt(const float* __restrict__ s, _Float16* __restrict__ d, int n) {
  int i = blockIdx.x * 256 + threadIdx.x;
  const int st = gridDim.x * 256;
  for (; i < n; i += st) d[i] = (_Float16)s[i];
}

// conv1_w (H,H,2) -> W1r[o][i]=w[o,i,0], W1r[o][1024+i]=w[o,i,1]
__global__ void k_w1r(const float* __restrict__ w, _Float16* __restrict__ d) {
  const int i = blockIdx.x * 256 + threadIdx.x;
  if (i >= 2097152) return;
  const int o = i >> 11, kk = i & 2047;
  const int src = (kk < 1024) ? (o * 2048 + kk * 2) : (o * 2048 + (kk - 1024) * 2 + 1);
  d[i] = (_Float16)w[src];
}

// embedding gather -> embpair[t][b] = [emb[t-1] | emb[t]] (f16), plus mask output
__global__ void k_emb(const int* __restrict__ tokens, const float* __restrict__ table,
                      _Float16* __restrict__ embpair, float* __restrict__ maskOut)
{
  const int tb = blockIdx.x;           // t*64 + b
  const int t = tb >> 6, b = tb & 63;
  const int tok = tokens[tb];
  const float* row = table + (size_t)tok * 1024;
  _Float16* dst1 = embpair + (size_t)tb * 2048 + 1024;
  for (int i = threadIdx.x; i < 1024; i += 256) {
    const _Float16 v = (_Float16)row[i];
    dst1[i] = v;
    if (t + 1 < 256) embpair[(size_t)(tb + 64) * 2048 + i] = v;
    if (t == 0)      embpair[(size_t)b * 2048 + i] = (_Float16)0.f;
  }
  if (threadIdx.x == 0) maskOut[tb] = (tok != 0) ? 1.f : 0.f;
}

// conv2 (grouped, ksize1) + sigmoid -> gate, gate_next
__global__ __launch_bounds__(128) void k_conv2(const _Float16* __restrict__ hcv,
                                               const float* __restrict__ w2, const float* __restrict__ b2,
                                               float* __restrict__ gate, float* __restrict__ gaten)
{
  const int r = blockIdx.x;            // t*64 + b
  const int wv = threadIdx.x >> 6, ln = threadIdx.x & 63;
  const _Float16* hr = hcv + (size_t)r * 1024 + wv * 512;
  const float* wr = w2 + wv * 512;
  float p = 0.f;
  for (int i = ln; i < 512; i += 64) p = fmaf((float)hr[i], wr[i], p);
  for (int off = 32; off > 0; off >>= 1) p += __shfl_down(p, off, 64);
  if (ln == 0) {
    const float v = sigm(p + b2[wv]);
    (wv ? gaten : gate)[r] = v;
  }
}

// mg/mgn cumprod masks (stored scan-order: [(t*64+b)*15 + s])
__global__ void k_masks(const float* __restrict__ gate, const float* __restrict__ gaten,
                        float* __restrict__ mg, float* __restrict__ mgn)
{
  const int i = blockIdx.x * 256 + threadIdx.x;
  if (i >= 16384) return;
  const int t = i >> 6, b = i & 63;
  const float gc = gate[i], gn = gaten[i];
  float p = 1.f, q = 1.f;
  for (int s = 0; s < 15; s++) {
    const float gh = (s <= t) ? gate[(t - s) * 64 + b] : 1e8f;
    p *= sigm((gc - gh) * 100.f + 5.f);
    q *= sigm((gn - gh) * 100.f + 5.f);
    mg[(size_t)i * 15 + s] = p;
    mgn[(size_t)i * 15 + s] = q;
  }
}

// ============================== host ==============================
extern "C" void kernel_launch(void* const* d_in, const int* in_sizes, int n_in,
                              void* d_out, int out_size, void* d_ws, size_t ws_size,
                              hipStream_t stream)
{
  (void)in_sizes; (void)n_in; (void)out_size; (void)ws_size;
  const int*   tokens = (const int*)d_in[0];
  const float* table  = (const float*)d_in[1];
  const float* w1     = (const float*)d_in[2];
  const float* c1b    = (const float*)d_in[3];
  const float* g1     = (const float*)d_in[4];
  const float* bt1    = (const float*)d_in[5];
  const float* w2     = (const float*)d_in[6];
  const float* c2b    = (const float*)d_in[7];
  const float* wih    = (const float*)d_in[8];
  const float* whh    = (const float*)d_in[9];
  const float* bih    = (const float*)d_in[10];
  const float* bhh    = (const float*)d_in[11];
  const float* wsm    = (const float*)d_in[12];
  const float* bsm    = (const float*)d_in[13];
  const float* wpd    = (const float*)d_in[14];
  const float* bpd    = (const float*)d_in[15];
  const float* ffw    = (const float*)d_in[16];
  const float* ffb    = (const float*)d_in[17];
  const float* ffg    = (const float*)d_in[18];
  const float* ffbt   = (const float*)d_in[19];

  float* outp    = (float*)d_out;            // 16384*1024
  float* maskOut = outp + 16777216;          // 16384

  char* wp_ = (char*)d_ws;
  auto alloc = [&](size_t b) { void* r = (void*)wp_; wp_ += (b + 255) & ~(size_t)255; return r; };

  _Float16* embpair  = (_Float16*)alloc(67108864);   // [16384][2048]; reused as xbuf in scan
  _Float16* hcv      = (_Float16*)alloc(33554432);   // [16384][1024]; reused as embkey
  _Float16* embgates = (_Float16*)alloc(134217728);  // [16384][4096]
  _Float16* wihF     = (_Float16*)alloc(16777216);   // 2*4096*1024
  _Float16* whhF     = (_Float16*)alloc(16777216);
  _Float16* wsmF     = (_Float16*)alloc(8388608);    // 2*1024*2048
  _Float16* wpdF     = (_Float16*)alloc(4194304);    // 1024*2048
  _Float16* ffwF     = (_Float16*)alloc(4194304);
  _Float16* w1rF     = (_Float16*)alloc(4194304);    // 1024*2048
  _Float16* h0h      = (_Float16*)alloc(131072);     // [64][1024]
  _Float16* h1h      = (_Float16*)alloc(131072);
  float* gate    = (float*)alloc(65536);
  float* gaten   = (float*)alloc(65536);
  float* mg      = (float*)alloc(983040);            // [16384][15]
  float* mgn     = (float*)alloc(983040);
  float* key1s   = (float*)alloc(262144);            // [64][1024]
  float* gates1i = (float*)alloc(1048576);           // [64][4096]
  float* keypred = (float*)alloc(262144);
  // contiguous zero-init block: 16-slot rings + proj rings + cached keys + barrier
  float* zb = (float*)alloc(51413120);               // 12,853,280 floats
  float* ringH0 = zb;                 // [16][64][1024]
  float* ringC0 = ringH0 + 1048576;
  float* ringH1 = ringC0 + 1048576;
  float* ringC1 = ringH1 + 1048576;
  float* P0     = ringC1 + 1048576;   // [16][64][4096]
  float* P1     = P0 + 4194304;
  float* kc0    = P1 + 4194304;       // [64][1024]
  float* kc1    = kc0 + 65536;
  float* kcp0   = kc1 + 65536;
  float* kcp1   = kcp0 + 65536;
  unsigned* bar = (unsigned*)(kcp1 + 65536);  // arrive[256*32] + release

  // aliases (consumed-in-setup buffers reused during scan)
  _Float16* xbuf   = embpair;   // [16384][2048] f16, written by pred from t=0
  _Float16* embkey = hcv;       // [16384][1024] f16, written after k_conv2 consumed hcv

  // ---- setup ----
  k_zero<<<4096, 256, 0, stream>>>(zb, 12853280);
  k_emb<<<16384, 256, 0, stream>>>(tokens, table, embpair, maskOut);
  k_cvt<<<8192, 256, 0, stream>>>(wih, wihF, 8388608);
  k_cvt<<<8192, 256, 0, stream>>>(whh, whhF, 8388608);
  k_cvt<<<8192, 256, 0, stream>>>(wsm, wsmF, 4194304);
  k_cvt<<<4096, 256, 0, stream>>>(wpd, wpdF, 2097152);
  k_cvt<<<4096, 256, 0, stream>>>(ffw, ffwF, 2097152);
  k_w1r<<<8192, 256, 0, stream>>>(w1, w1rF);
  // conv1: relu(gamma*(A@W1r^T + c1b) + beta)
  gemm_bt<1, _Float16><<<dim3(16, 256), 256, 0, stream>>>(embpair, 2048, w1rF, 2048, hcv, 1024, 2048, g1, c1b, bt1);
  k_conv2<<<16384, 128, 0, stream>>>(hcv, w2, c2b, gate, gaten);
  k_masks<<<64, 256, 0, stream>>>(gate, gaten, mg, mgn);
  // embgates = emb@wih0^T + bih0 + bhh0 ; embkey = emb@Wsumm0_a^T + bsumm0
  gemm_bt<0, _Float16><<<dim3(64, 256), 256, 0, stream>>>(embpair + 1024, 2048, wihF, 1024, embgates, 4096, 1024, bih, bhh, nullptr);
  gemm_bt<0, _Float16><<<dim3(16, 256), 256, 0, stream>>>(embpair + 1024, 2048, wsmF, 2048, embkey, 1024, 1024, bsm, nullptr, nullptr);

  // ---- persistent scan (plain launch; 256 blocks provably all co-resident) ----
  ScanArgs sa;
  sa.embkey = embkey; sa.embgates = embgates;
  sa.wihF = wihF; sa.whhF = whhF; sa.wsmF = wsmF; sa.wpdF = wpdF;
  sa.mg = mg; sa.mgn = mgn; sa.bih = bih; sa.bhh = bhh; sa.bsm = bsm; sa.bpd = bpd;
  sa.ringH0 = ringH0; sa.ringC0 = ringC0; sa.ringH1 = ringH1; sa.ringC1 = ringC1;
  sa.P0 = P0; sa.P1 = P1;
  sa.kc0 = kc0; sa.kc1 = kc1; sa.kcp0 = kcp0; sa.kcp1 = kcp1;
  sa.key1s = key1s; sa.gates1i = gates1i; sa.keypred = keypred;
  sa.h0h = h0h; sa.h1h = h1h; sa.xbuf = xbuf;
  sa.bar = bar;
  k_scan<<<dim3(256), dim3(256), 0, stream>>>(sa);

  // ---- epilogue FFD: out = tanh(ffg*(x@ffw^T + ffb) + ffbt) ----
  gemm_bt<2, float><<<dim3(16, 256), 256, 0, stream>>>(xbuf, 2048, ffwF, 2048, outp, 1024, 2048, ffg, ffb, ffbt);
}